// Round 4
// baseline (254.688 us; speedup 1.0000x reference)
//
#include <hip/hip_runtime.h>

// SelfAttention: GN -> 1x1 QKV -> softmax attention (HW=1024) -> 1x1 proj + residual
// B=16, C=512, HW=1024, GROUPS=32, EPS=1e-5, scale=C^-0.5
//
// Round 12: 8-wave blocks. R9-R11 post-mortem: 4-wave blocks = 1 wave/SIMD/block, so
// within a block a SIMD has NO overlap partner between barriers (ds_read -> lgkm wait
// -> MFMA fully serial); R11 proved cross-block TLP doesn't fill the stalls (occ 17->34%,
// dur flat). MFMA const recalibrated: 16x16x32 f16 = ~19 cyc (2.5PF/1024 SIMD), so
// MfmaUtil 19% == 55us vs 10.3us floor. Fix = HK 8-wave structure: 128x256 tile, 8
// waves of 64x64 (2 waves/SIMD in-block -> wave A's LDS wait overlaps wave B's MFMA),
// 4-buffer LDS (96KB, 1 block/CU), prefetch distance 3, counted vmcnt(6/3/0), setprio(1)
// around MFMA cluster (T5 pays only with role-split waves, m218b). Same verified
// conflict-free chunk swizzle (conflicts=0 since R9).
// Layouts (all [free][K]):
//   xnT [b][hw][c], qkT [b][hw][q|k], v [b][c][hw], S/P [b][i][j], aoutT [b][hw][c]

typedef _Float16 f16;
typedef _Float16 f16x8 __attribute__((ext_vector_type(8)));
typedef _Float16 f16x4 __attribute__((ext_vector_type(4)));
typedef float fx4 __attribute__((ext_vector_type(4)));

__device__ __forceinline__ void gload16(const f16* g, f16* l) {
    __builtin_amdgcn_global_load_lds((const __attribute__((address_space(1))) void*)g,
                                     (__attribute__((address_space(3))) void*)l, 16, 0, 0);
}

// ---------------- weight convert: fp32 -> f16, n4 float4 chunks ----------------
__global__ __launch_bounds__(256)
void wconv_kernel(const float* __restrict__ w, f16* __restrict__ o, int n4)
{
    int i = blockIdx.x * 256 + threadIdx.x;
    if (i < n4) {
        float4 v = *(const float4*)(w + i * 4);
        f16x4 h;
        h[0] = (f16)v.x; h[1] = (f16)v.y; h[2] = (f16)v.z; h[3] = (f16)v.w;
        *(f16x4*)(o + i * 4) = h;
    }
}

// ---------------- GroupNorm: x fp32 [16][512][1024] -> xnT f16 [16][1024][512] ----------------
__global__ __launch_bounds__(256)
void groupnorm_kernel(const float* __restrict__ x, const float* __restrict__ gamma,
                      const float* __restrict__ beta, f16* __restrict__ xnT)
{
    __shared__ float red[256], red2[256];
    __shared__ float mu_s, rs_s;
    __shared__ __align__(16) f16 T[16][1040];  // [ch][hw], padded
    const int blk = blockIdx.x;                // b*32 + g
    const int b = blk >> 5, g = blk & 31;
    const long base = (long)blk * 16384;       // 16 ch * 1024 hw
    const int tid = threadIdx.x;
    const float4* xv = (const float4*)(x + base);

    float4 xr[16];
    float s = 0.f, s2 = 0.f;
#pragma unroll
    for (int i = 0; i < 16; i++) {
        float4 v = xv[tid + i * 256];
        xr[i] = v;
        s  += v.x + v.y + v.z + v.w;
        s2 += v.x * v.x + v.y * v.y + v.z * v.z + v.w * v.w;
    }
    red[tid] = s; red2[tid] = s2;
    __syncthreads();
    for (int off = 128; off > 0; off >>= 1) {
        if (tid < off) { red[tid] += red[tid + off]; red2[tid] += red2[tid + off]; }
        __syncthreads();
    }
    if (tid == 0) {
        float mu = red[0] * (1.f / 16384.f);
        float var = red2[0] * (1.f / 16384.f) - mu * mu;
        mu_s = mu;
        rs_s = rsqrtf(var + 1e-5f);
    }
    __syncthreads();
    const float mu = mu_s, rs = rs_s;

#pragma unroll
    for (int i = 0; i < 16; i++) {
        float gm = gamma[g * 16 + i] * rs;
        float bt = beta[g * 16 + i] - mu * gm;
        float4 v = xr[i];
        f16x4 o;
        o[0] = (f16)(v.x * gm + bt);
        o[1] = (f16)(v.y * gm + bt);
        o[2] = (f16)(v.z * gm + bt);
        o[3] = (f16)(v.w * gm + bt);
        *(f16x4*)&T[i][tid * 4] = o;
    }
    __syncthreads();
#pragma unroll
    for (int i = 0; i < 8; i++) {
        int idx = tid + i * 256;
        int hw = idx >> 1;
        int half8 = (idx & 1) * 8;
        f16x8 o;
#pragma unroll
        for (int j = 0; j < 8; j++) o[j] = T[half8 + j][hw];
        long dst = ((long)b * 1024 + hw) * 512 + g * 16 + half8;
        *(f16x8*)(xnT + dst) = o;
    }
}

// ---------------- Row softmax over j: S f16 [16][1024][1024], one wave per row ----------------
__global__ __launch_bounds__(256)
void softmax_kernel(f16* __restrict__ S)
{
    const int wid = blockIdx.x * 4 + (threadIdx.x >> 6);
    const int lane = threadIdx.x & 63;
    f16* p = S + (long)wid * 1024 + lane * 16;
    f16x8 h0 = *(const f16x8*)p;
    f16x8 h1 = *(const f16x8*)(p + 8);
    float v[16];
#pragma unroll
    for (int i = 0; i < 8; i++) { v[i] = (float)h0[i]; v[8 + i] = (float)h1[i]; }
    float mx = v[0];
#pragma unroll
    for (int i = 1; i < 16; i++) mx = fmaxf(mx, v[i]);
    for (int off = 32; off > 0; off >>= 1) mx = fmaxf(mx, __shfl_xor(mx, off, 64));
    float sum = 0.f;
#pragma unroll
    for (int i = 0; i < 16; i++) { v[i] = __expf(v[i] - mx); sum += v[i]; }
    for (int off = 32; off > 0; off >>= 1) sum += __shfl_xor(sum, off, 64);
    const float inv = 1.f / sum;
#pragma unroll
    for (int i = 0; i < 8; i++) { h0[i] = (f16)(v[i] * inv); h1[i] = (f16)(v[8 + i] * inv); }
    *(f16x8*)p = h0;
    *(f16x8*)(p + 8) = h1;
}

// ----- 128x256 MFMA GEMM, 8 waves of 64x64, 4-buffer counted-vmcnt pipeline, setprio -----
// A stored [M][K] f16 (lda), B stored [N][K] f16 (ldb); async staged via global_load_lds w16.
// Conflict-free chunk swizzle: LDS[row][c] holds global chunk c ^ ((row>>1)&3).
// Generic XCD remap: one batch pinned per XCD at a time; within batch, n sweeps fastest
// (A-tile reuse). MODE 0: f16 out C[m][n] ld=N, *alpha. MODE 1: QKV split (q,k -> qkT;
// v transposed -> C2p; bias[n]). MODE 2: fp32 out + bias[m] + resid.
template<int MODE>
__global__ __launch_bounds__(512)
void gemm_kernel(const f16* __restrict__ Ap, const f16* __restrict__ Bp,
                 void* __restrict__ Cp, f16* __restrict__ C2p,
                 const float* __restrict__ bias, const float* __restrict__ resid,
                 float alpha, int M, int N, int K, int lda, int ldb,
                 long sAb, long sBb, long sCb)
{
    __shared__ __align__(16) f16 As[4][128 * 32];   // 32 KB
    __shared__ __align__(16) f16 Bs[4][256 * 32];   // 64 KB

    // ---- XCD remap: linear -> (b, mIdx, nIdx); 8 XCDs, linear&7 = XCD ----
    const int linear = (blockIdx.z * gridDim.y + blockIdx.y) * gridDim.x + blockIdx.x;
    const int nTiles = gridDim.x, nm = gridDim.x * gridDim.y;   // blocks per batch
    const int x7 = linear & 7, slot = linear >> 3;
    const int b = x7 + 8 * (slot / nm);
    const int rem = slot % nm;
    const int mIdx = rem / nTiles, nIdx = rem % nTiles;
    const int m0 = mIdx * 128, n0 = nIdx * 256;

    const int tid = threadIdx.x;
    const int wave = tid >> 6, lane = tid & 63;
    const int quad = lane >> 4, l15 = lane & 15;
    const int wm = (wave >> 2) * 64, wn = (wave & 3) * 64;
    // read-side swizzle: global K-chunk `quad` of row (..+l15) lives at LDS chunk
    // quad ^ ((l15>>1)&3)  (base rows are multiples of 16 so only l15 matters)
    const int chunkoff = (quad ^ ((l15 >> 1) & 3)) * 8;

    const f16* Ag = Ap + (long)b * sAb;
    const f16* Bg = Bp + (long)b * sBb;

    // staging: lane -> LDS row +si, chunk sj (linear dest); source pre-swizzled
    const int si = lane >> 2, sj = lane & 3;
    const int swz = (sj ^ ((si >> 1) & 3)) * 8;
    const int RA = wave * 16;                       // A: 128 rows, 1 instr/wave
    const int RB = wave * 32;                       // B: 256 rows, 2 instr/wave
    const f16* agA = Ag + (long)(m0 + RA + si) * lda + swz;
    const f16* agB = Bg + (long)(n0 + RB + si) * ldb + swz;

    fx4 acc[4][4] = {};
    const int nIter = K >> 5;

    // 3 vmem ops per STAGE per wave; prefetch distance 3 -> steady-state vmcnt(6)
#define STAGE(buf, kOff)                                              \
    { gload16(agA + (kOff),            &As[buf][RA * 32]);            \
      gload16(agB + (kOff),            &Bs[buf][RB * 32]);            \
      gload16(agB + 16 * ldb + (kOff), &Bs[buf][(RB + 16) * 32]); }

    STAGE(0, 0)
    if (nIter > 1) STAGE(1, 32)
    if (nIter > 2) STAGE(2, 64)

    for (int it = 0; it < nIter; ++it) {
        // wait for STAGE(it): in-order retire; leave newer STAGEs in flight
        const int ahead = nIter - 1 - it;
        if (ahead == 0)      { asm volatile("s_waitcnt vmcnt(0)" ::: "memory"); }
        else if (ahead == 1) { asm volatile("s_waitcnt vmcnt(3)" ::: "memory"); }
        else                 { asm volatile("s_waitcnt vmcnt(6)" ::: "memory"); }
        __builtin_amdgcn_s_barrier();
        if (it + 3 < nIter) { STAGE((it + 3) & 3, (it + 3) << 5) }
        const int cur = it & 3;
        f16x8 bf[4];
#pragma unroll
        for (int tn = 0; tn < 4; tn++)
            bf[tn] = *(const f16x8*)&Bs[cur][(wn + tn * 16 + l15) * 32 + chunkoff];
        f16x8 af[4];
#pragma unroll
        for (int tm = 0; tm < 4; tm++)
            af[tm] = *(const f16x8*)&As[cur][(wm + tm * 16 + l15) * 32 + chunkoff];
        __builtin_amdgcn_s_setprio(1);
#pragma unroll
        for (int tm = 0; tm < 4; tm++)
#pragma unroll
            for (int tn = 0; tn < 4; tn++)
                acc[tm][tn] = __builtin_amdgcn_mfma_f32_16x16x32_f16(af[tm], bf[tn], acc[tm][tn], 0, 0, 0);
        __builtin_amdgcn_s_setprio(0);
    }
#undef STAGE

    // ---- epilogue: D[row = quad*4+r][col = l15] per 16x16 tile
    if (MODE == 1 && n0 >= 1024) {
        // v-part: write transposed to v[b][c][hw], vectorized f16x4 along hw(=m)
#pragma unroll
        for (int tm = 0; tm < 4; tm++)
#pragma unroll
        for (int tn = 0; tn < 4; tn++) {
            int gc = n0 + wn + tn * 16 + l15;
            int gr0 = m0 + wm + tm * 16 + quad * 4;
            float bs = bias[gc];
            f16x4 o;
#pragma unroll
            for (int r = 0; r < 4; r++) o[r] = (f16)(acc[tm][tn][r] + bs);
            *(f16x4*)(C2p + (long)b * 524288 + (long)(gc - 1024) * 1024 + gr0) = o;
        }
        return;
    }
#pragma unroll
    for (int tm = 0; tm < 4; tm++)
#pragma unroll
    for (int tn = 0; tn < 4; tn++) {
        int gc = n0 + wn + tn * 16 + l15;
#pragma unroll
        for (int r = 0; r < 4; r++) {
            int gr = m0 + wm + tm * 16 + quad * 4 + r;
            float v = acc[tm][tn][r];
            if (MODE == 0) {
                v *= alpha;
                ((f16*)Cp)[(long)b * sCb + (long)gr * N + gc] = (f16)v;
            } else if (MODE == 1) {
                v += bias[gc];
                ((f16*)Cp)[(long)b * 1048576 + (long)gr * 1024 + gc] = (f16)v;
            } else {  // MODE 2
                v += bias[gr];
                long idx = (long)b * sCb + (long)gr * N + gc;
                v += resid[idx];
                ((float*)Cp)[idx] = v;
            }
        }
    }
}

extern "C" void kernel_launch(void* const* d_in, const int* in_sizes, int n_in,
                              void* d_out, int out_size, void* d_ws, size_t ws_size,
                              hipStream_t stream)
{
    const float* x      = (const float*)d_in[0];
    const float* gamma  = (const float*)d_in[1];
    const float* beta   = (const float*)d_in[2];
    const float* w_qkv  = (const float*)d_in[3];
    const float* b_qkv  = (const float*)d_in[4];
    const float* w_proj = (const float*)d_in[5];
    const float* b_proj = (const float*)d_in[6];
    float* out = (float*)d_out;

    char* ws = (char*)d_ws;
    f16* xnT   = (f16*)(ws);                 // 16 MB : [16][1024 hw][512 c]
    f16* qkT   = (f16*)(ws + (16L << 20));   // 32 MB : [16][1024 hw][1024 (q|k)]
    f16* vbuf  = (f16*)(ws + (48L << 20));   // 16 MB : [16][512 c][1024 hw]
    f16* S     = (f16*)(ws + (64L << 20));   // 32 MB : [16][1024 i][1024 j]
    f16* aoutT = (f16*)(ws + (96L << 20));   // 16 MB : [16][1024 hw][512 c]
    f16* wqkvh = S;                          // 1.5 MB; dead before scores writes S
    f16* wprjh = xnT;                        // 0.5 MB; written after QKV consumes xnT

    // 0) convert w_qkv fp32 -> f16
    wconv_kernel<<<768, 256, 0, stream>>>(w_qkv, wqkvh, 196608);

    // 1) GroupNorm -> xnT
    groupnorm_kernel<<<512, 256, 0, stream>>>(x, gamma, beta, xnT);

    // 2) QKV: C[m=hw][n=o] = xnT[hw][c] . w_qkv[o][c]; q,k -> qkT, v -> vbuf
    gemm_kernel<1><<<dim3(6, 8, 16), 512, 0, stream>>>(
        xnT, wqkvh, qkT, vbuf, b_qkv, nullptr, 1.0f,
        1024, 1536, 512, 512, 512,
        524288L, 0L, 0L);

    // 2b) convert w_proj fp32 -> f16 (xnT dead after QKV)
    wconv_kernel<<<256, 256, 0, stream>>>(w_proj, wprjh, 65536);

    // 3) Scores: S[i][j] = scale * q[i][c] . k[j][c]
    gemm_kernel<0><<<dim3(4, 8, 16), 512, 0, stream>>>(
        qkT, qkT + 512, S, nullptr, nullptr, nullptr, 0.04419417382415922f,
        1024, 1024, 512, 1024, 1024,
        1048576L, 1048576L, 1048576L);

    // 4) Softmax over j
    softmax_kernel<<<4096, 256, 0, stream>>>(S);

    // 5) PV: aoutT[i][c] = P[i][j] . v[c][j]
    gemm_kernel<0><<<dim3(2, 8, 16), 512, 0, stream>>>(
        S, vbuf, aoutT, nullptr, nullptr, nullptr, 1.0f,
        1024, 512, 1024, 1024, 1024,
        1048576L, 524288L, 524288L);

    // 6) Proj: out[o][hw] = w_proj[o][c] . aoutT[hw][c] + b_proj[o] + x
    gemm_kernel<2><<<dim3(4, 4, 16), 512, 0, stream>>>(
        wprjh, aoutT, out, nullptr, b_proj, x, 1.0f,
        512, 1024, 512, 512, 512,
        0L, 524288L, 524288L);
}

// Round 5
// 229.986 us; speedup vs baseline: 1.1074x; 1.1074x over previous
//
#include <hip/hip_runtime.h>

// SelfAttention: GN -> 1x1 QKV -> softmax attention (HW=1024) -> 1x1 proj + residual
// B=16, C=512, HW=1024, GROUPS=32, EPS=1e-5, scale=C^-0.5
//
// Round 13: persistent strip-streaming GEMM with fine-phase schedule. R9-R12: five
// schedules all 49-57us, all pipes <20%. Root cause: 16 K-iters/block -> ramp+drain+
// epilogue churn dominates (m97 sustains 245cyc/iter only with 128-iter streams), and
// coarse phases without fine ds/STAGE/MFMA interleave hurt (m196). This round:
//  - grid = 256 persistent blocks (XCD-bijective swizzle), 8 waves, 1 block/CU;
//    each block STREAMS T tiles (QKV 3, scores 2, PV/proj 1) through one pipeline
//    that never drains between tiles (per-block stream: 48/64/32/16 K32-steps).
//  - tile 256x128, wave tile 64x64 (proven acc[4][4] math), BK=64 staged as two
//    K32 halves; 3 gloads/wave/half; ledger: stage H(s+2) during s, vmcnt(3) BEFORE
//    the closing barrier (proves H(s+1) for ALL waves - m201 wait-then-barrier);
//    vmcnt(0) once per tile.
//  - per half-step 2 fine phases: {6 ds_read, 2 gload, bar, 8 MFMA, bar} then
//    {2 ds_read, 1 gload, 8 MFMA, vmcnt, bar}; setprio(1) around MFMA clusters.
//  - LDS 96KB = As[4][256*32] + Bs[4][128*32]; R9's HW-verified zero-conflict
//    chunk swizzle (identical 64B-row geometry).
// Layouts (all [free][K]):
//   xnT [b][hw][c], qkT [b][hw][q|k], v [b][c][hw], S/P [b][i][j], aoutT [b][hw][c]

typedef _Float16 f16;
typedef _Float16 f16x8 __attribute__((ext_vector_type(8)));
typedef _Float16 f16x4 __attribute__((ext_vector_type(4)));
typedef float fx4 __attribute__((ext_vector_type(4)));

__device__ __forceinline__ void gload16(const f16* g, f16* l) {
    __builtin_amdgcn_global_load_lds((const __attribute__((address_space(1))) void*)g,
                                     (__attribute__((address_space(3))) void*)l, 16, 0, 0);
}

// ---------------- weight convert: fp32 -> f16, n4 float4 chunks ----------------
__global__ __launch_bounds__(256)
void wconv_kernel(const float* __restrict__ w, f16* __restrict__ o, int n4)
{
    int i = blockIdx.x * 256 + threadIdx.x;
    if (i < n4) {
        float4 v = *(const float4*)(w + i * 4);
        f16x4 h;
        h[0] = (f16)v.x; h[1] = (f16)v.y; h[2] = (f16)v.z; h[3] = (f16)v.w;
        *(f16x4*)(o + i * 4) = h;
    }
}

// ---------------- GroupNorm: x fp32 [16][512][1024] -> xnT f16 [16][1024][512] ----------------
__global__ __launch_bounds__(256)
void groupnorm_kernel(const float* __restrict__ x, const float* __restrict__ gamma,
                      const float* __restrict__ beta, f16* __restrict__ xnT)
{
    __shared__ float red[256], red2[256];
    __shared__ float mu_s, rs_s;
    __shared__ __align__(16) f16 T[16][1040];  // [ch][hw], padded
    const int blk = blockIdx.x;                // b*32 + g
    const int b = blk >> 5, g = blk & 31;
    const long base = (long)blk * 16384;       // 16 ch * 1024 hw
    const int tid = threadIdx.x;
    const float4* xv = (const float4*)(x + base);

    float4 xr[16];
    float s = 0.f, s2 = 0.f;
#pragma unroll
    for (int i = 0; i < 16; i++) {
        float4 v = xv[tid + i * 256];
        xr[i] = v;
        s  += v.x + v.y + v.z + v.w;
        s2 += v.x * v.x + v.y * v.y + v.z * v.z + v.w * v.w;
    }
    red[tid] = s; red2[tid] = s2;
    __syncthreads();
    for (int off = 128; off > 0; off >>= 1) {
        if (tid < off) { red[tid] += red[tid + off]; red2[tid] += red2[tid + off]; }
        __syncthreads();
    }
    if (tid == 0) {
        float mu = red[0] * (1.f / 16384.f);
        float var = red2[0] * (1.f / 16384.f) - mu * mu;
        mu_s = mu;
        rs_s = rsqrtf(var + 1e-5f);
    }
    __syncthreads();
    const float mu = mu_s, rs = rs_s;

#pragma unroll
    for (int i = 0; i < 16; i++) {
        float gm = gamma[g * 16 + i] * rs;
        float bt = beta[g * 16 + i] - mu * gm;
        float4 v = xr[i];
        f16x4 o;
        o[0] = (f16)(v.x * gm + bt);
        o[1] = (f16)(v.y * gm + bt);
        o[2] = (f16)(v.z * gm + bt);
        o[3] = (f16)(v.w * gm + bt);
        *(f16x4*)&T[i][tid * 4] = o;
    }
    __syncthreads();
#pragma unroll
    for (int i = 0; i < 8; i++) {
        int idx = tid + i * 256;
        int hw = idx >> 1;
        int half8 = (idx & 1) * 8;
        f16x8 o;
#pragma unroll
        for (int j = 0; j < 8; j++) o[j] = T[half8 + j][hw];
        long dst = ((long)b * 1024 + hw) * 512 + g * 16 + half8;
        *(f16x8*)(xnT + dst) = o;
    }
}

// ---------------- Row softmax over j: S f16 [16][1024][1024], one wave per row ----------------
__global__ __launch_bounds__(256)
void softmax_kernel(f16* __restrict__ S)
{
    const int wid = blockIdx.x * 4 + (threadIdx.x >> 6);
    const int lane = threadIdx.x & 63;
    f16* p = S + (long)wid * 1024 + lane * 16;
    f16x8 h0 = *(const f16x8*)p;
    f16x8 h1 = *(const f16x8*)(p + 8);
    float v[16];
#pragma unroll
    for (int i = 0; i < 8; i++) { v[i] = (float)h0[i]; v[8 + i] = (float)h1[i]; }
    float mx = v[0];
#pragma unroll
    for (int i = 1; i < 16; i++) mx = fmaxf(mx, v[i]);
    for (int off = 32; off > 0; off >>= 1) mx = fmaxf(mx, __shfl_xor(mx, off, 64));
    float sum = 0.f;
#pragma unroll
    for (int i = 0; i < 16; i++) { v[i] = __expf(v[i] - mx); sum += v[i]; }
    for (int off = 32; off > 0; off >>= 1) sum += __shfl_xor(sum, off, 64);
    const float inv = 1.f / sum;
#pragma unroll
    for (int i = 0; i < 8; i++) { h0[i] = (f16)(v[i] * inv); h1[i] = (f16)(v[8 + i] * inv); }
    *(f16x8*)p = h0;
    *(f16x8*)(p + 8) = h1;
}

// -------- persistent 256x128 MFMA GEMM, 8 waves of 64x64, fine-phase streamed pipeline -------
// A stored [M][K] f16 (lda), B stored [N][K] f16 (ldb); async staged via global_load_lds w16.
// Batch-folded tile space: id -> b = id/tpb, r = id%tpb, m0 = (r%nm)*256, n0 = (r/nm)*128.
// K staged in 32-wide halves H_s (s = 0..H-1, H = K/32), LDS slot = s&3 (2 bufs x 2 halves).
// MODE 0: f16 out C[m][n] ld=N, *alpha. MODE 1: QKV split (q,k -> qkT; v transposed -> C2p;
// bias[n]). MODE 2: fp32 out + bias[m] + resid.
template<int MODE>
__global__ __launch_bounds__(512, 2)
void pgemm_kernel(const f16* __restrict__ Ap, const f16* __restrict__ Bp,
                  void* __restrict__ Cp, f16* __restrict__ C2p,
                  const float* __restrict__ bias, const float* __restrict__ resid,
                  float alpha, int K, int lda, int ldb, int N,
                  int nm, int tpb, int nT,
                  long sAb, long sBb, long sCb)
{
    __shared__ __align__(16) f16 As[4][256 * 32];   // 64 KB (2 bufs x 2 K-halves)
    __shared__ __align__(16) f16 Bs[4][128 * 32];   // 32 KB

    // XCD-bijective block remap: 256 blocks -> 8 XCDs x 32 contiguous ids
    const int blk = (blockIdx.x & 7) * 32 + (blockIdx.x >> 3);

    const int tid = threadIdx.x;
    const int wave = tid >> 6, lane = tid & 63;
    const int quad = lane >> 4, l15 = lane & 15;
    const int wm = (wave >> 1) * 64, wn = (wave & 1) * 64;
    // read-side chunk swizzle (HW-verified 0 conflicts since R9): chunk = quad ^ ((row>>1)&3)
    const int chunkoff = (quad ^ ((l15 >> 1) & 3)) * 8;

    // staging: per gload instr, lane -> local row rl = lane>>2 (16 rows), chunk = lane&3,
    // source column pre-swizzled to match read-side swizzle
    const int rl = lane >> 2;
    const int swzc = ((lane & 3) ^ ((rl >> 1) & 3)) * 8;
    const int RA = wave * 32;     // A: 256 rows / 8 waves, 2 instrs
    const int RB = wave * 16;     // B: 128 rows / 8 waves, 1 instr
    const int H = K >> 5;

    for (int id = blk; id < nT; id += 256) {
        const int b  = id / tpb, r = id % tpb;
        const int m0 = (r % nm) * 256, n0 = (r / nm) * 128;
        const f16* agA = Ap + (long)b * sAb + (long)(m0 + RA + rl) * lda + swzc;
        const f16* agB = Bp + (long)b * sBb + (long)(n0 + RB + rl) * ldb + swzc;

        // ---- prologue: stage H0 (oldest) then H1; prove H0 before entering loop ----
        gload16(agA,                 &As[0][RA * 32]);
        gload16(agA + 16 * lda,      &As[0][(RA + 16) * 32]);
        gload16(agB,                 &Bs[0][RB * 32]);
        gload16(agA + 32,            &As[1][RA * 32]);
        gload16(agA + 16 * lda + 32, &As[1][(RA + 16) * 32]);
        gload16(agB + 32,            &Bs[1][RB * 32]);
        asm volatile("s_waitcnt vmcnt(3)" ::: "memory");
        __builtin_amdgcn_s_barrier();

        fx4 acc[4][4] = {};
        for (int s = 0; s < H; ++s) {
            const f16* Ab = &As[s & 3][0];
            const f16* Bb = &Bs[s & 3][0];
            const bool pre = (s + 2 < H);
            // ---- phase 0: A frags + B lo-half frags; stage A of H_{s+2} ----
            f16x8 af[4], bf[4];
#pragma unroll
            for (int fm = 0; fm < 4; fm++)
                af[fm] = *(const f16x8*)&Ab[(wm + fm * 16 + l15) * 32 + chunkoff];
#pragma unroll
            for (int fn = 0; fn < 2; fn++)
                bf[fn] = *(const f16x8*)&Bb[(wn + fn * 16 + l15) * 32 + chunkoff];
            if (pre) {
                f16* d = &As[(s + 2) & 3][0];
                gload16(agA + (long)(s + 2) * 32,            d + RA * 32);
                gload16(agA + 16 * lda + (long)(s + 2) * 32, d + (RA + 16) * 32);
            }
            __builtin_amdgcn_s_barrier();
            __builtin_amdgcn_s_setprio(1);
#pragma unroll
            for (int fm = 0; fm < 4; fm++)
#pragma unroll
                for (int fn = 0; fn < 2; fn++)
                    acc[fm][fn] = __builtin_amdgcn_mfma_f32_16x16x32_f16(af[fm], bf[fn], acc[fm][fn], 0, 0, 0);
            __builtin_amdgcn_s_setprio(0);
            __builtin_amdgcn_s_barrier();
            // ---- phase 1: B hi-half frags; stage B of H_{s+2}; prove H_{s+1} ----
#pragma unroll
            for (int fn = 2; fn < 4; fn++)
                bf[fn] = *(const f16x8*)&Bb[(wn + fn * 16 + l15) * 32 + chunkoff];
            if (pre)
                gload16(agB + (long)(s + 2) * 32, &Bs[(s + 2) & 3][RB * 32]);
            __builtin_amdgcn_s_setprio(1);
#pragma unroll
            for (int fm = 0; fm < 4; fm++)
#pragma unroll
                for (int fn = 2; fn < 4; fn++)
                    acc[fm][fn] = __builtin_amdgcn_mfma_f32_16x16x32_f16(af[fm], bf[fn], acc[fm][fn], 0, 0, 0);
            __builtin_amdgcn_s_setprio(0);
            if (pre)               { asm volatile("s_waitcnt vmcnt(3)" ::: "memory"); }
            else if (s == H - 2)   { asm volatile("s_waitcnt vmcnt(0)" ::: "memory"); }
            __builtin_amdgcn_s_barrier();
        }

        // ---- epilogue: D[row = quad*4+r][col = l15] per 16x16 tile ----
        if (MODE == 1 && n0 >= 1024) {
            // v-part: write transposed to v[b][c][hw], vectorized f16x4 along hw(=m)
#pragma unroll
            for (int tm = 0; tm < 4; tm++)
#pragma unroll
            for (int tn = 0; tn < 4; tn++) {
                int gc = n0 + wn + tn * 16 + l15;
                int gr0 = m0 + wm + tm * 16 + quad * 4;
                float bs = bias[gc];
                f16x4 o;
#pragma unroll
                for (int rr = 0; rr < 4; rr++) o[rr] = (f16)(acc[tm][tn][rr] + bs);
                *(f16x4*)(C2p + (long)b * 524288 + (long)(gc - 1024) * 1024 + gr0) = o;
            }
        } else {
#pragma unroll
            for (int tm = 0; tm < 4; tm++)
#pragma unroll
            for (int tn = 0; tn < 4; tn++) {
                int gc = n0 + wn + tn * 16 + l15;
#pragma unroll
                for (int rr = 0; rr < 4; rr++) {
                    int gr = m0 + wm + tm * 16 + quad * 4 + rr;
                    float v = acc[tm][tn][rr];
                    if (MODE == 0) {
                        v *= alpha;
                        ((f16*)Cp)[(long)b * sCb + (long)gr * N + gc] = (f16)v;
                    } else if (MODE == 1) {
                        v += bias[gc];
                        ((f16*)Cp)[(long)b * 1048576 + (long)gr * 1024 + gc] = (f16)v;
                    } else {  // MODE 2
                        v += bias[gr];
                        long idx = (long)b * sCb + (long)gr * N + gc;
                        v += resid[idx];
                        ((float*)Cp)[idx] = v;
                    }
                }
            }
        }
    }
}

extern "C" void kernel_launch(void* const* d_in, const int* in_sizes, int n_in,
                              void* d_out, int out_size, void* d_ws, size_t ws_size,
                              hipStream_t stream)
{
    const float* x      = (const float*)d_in[0];
    const float* gamma  = (const float*)d_in[1];
    const float* beta   = (const float*)d_in[2];
    const float* w_qkv  = (const float*)d_in[3];
    const float* b_qkv  = (const float*)d_in[4];
    const float* w_proj = (const float*)d_in[5];
    const float* b_proj = (const float*)d_in[6];
    float* out = (float*)d_out;

    char* ws = (char*)d_ws;
    f16* xnT   = (f16*)(ws);                 // 16 MB : [16][1024 hw][512 c]
    f16* qkT   = (f16*)(ws + (16L << 20));   // 32 MB : [16][1024 hw][1024 (q|k)]
    f16* vbuf  = (f16*)(ws + (48L << 20));   // 16 MB : [16][512 c][1024 hw]
    f16* S     = (f16*)(ws + (64L << 20));   // 32 MB : [16][1024 i][1024 j]
    f16* aoutT = (f16*)(ws + (96L << 20));   // 16 MB : [16][1024 hw][512 c]
    f16* wqkvh = S;                          // 1.5 MB; dead before scores writes S
    f16* wprjh = xnT;                        // 0.5 MB; written after QKV consumes xnT

    // 0) convert w_qkv fp32 -> f16
    wconv_kernel<<<768, 256, 0, stream>>>(w_qkv, wqkvh, 196608);

    // 1) GroupNorm -> xnT
    groupnorm_kernel<<<512, 256, 0, stream>>>(x, gamma, beta, xnT);

    // 2) QKV: C[m=hw][n=o] = xnT[hw][c] . w_qkv[o][c]; q,k -> qkT, v -> vbuf
    //    per-batch tiles: nm=4, nn=12, tpb=48, total 768 (T=3 per block)
    pgemm_kernel<1><<<256, 512, 0, stream>>>(
        xnT, wqkvh, qkT, vbuf, b_qkv, nullptr, 1.0f,
        512, 512, 512, 1536,
        4, 48, 768,
        524288L, 0L, 0L);

    // 2b) convert w_proj fp32 -> f16 (xnT dead after QKV)
    wconv_kernel<<<256, 256, 0, stream>>>(w_proj, wprjh, 65536);

    // 3) Scores: S[i][j] = scale * q[i][c] . k[j][c]; nm=4, nn=8, tpb=32, total 512 (T=2)
    pgemm_kernel<0><<<256, 512, 0, stream>>>(
        qkT, qkT + 512, S, nullptr, nullptr, nullptr, 0.04419417382415922f,
        512, 1024, 1024, 1024,
        4, 32, 512,
        1048576L, 1048576L, 1048576L);

    // 4) Softmax over j
    softmax_kernel<<<4096, 256, 0, stream>>>(S);

    // 5) PV: aoutT[i][c] = P[i][j] . v[c][j]; nm=4, nn=4, tpb=16, total 256 (T=1), K=1024
    pgemm_kernel<0><<<256, 512, 0, stream>>>(
        S, vbuf, aoutT, nullptr, nullptr, nullptr, 1.0f,
        1024, 1024, 1024, 512,
        4, 16, 256,
        1048576L, 524288L, 524288L);

    // 6) Proj: out[o][hw] = w_proj[o][c] . aoutT[hw][c] + b_proj[o] + x
    //    nm=2, nn=8, tpb=16, total 256 (T=1)
    pgemm_kernel<2><<<256, 512, 0, stream>>>(
        wprjh, aoutT, out, nullptr, b_proj, x, 1.0f,
        512, 512, 512, 1024,
        2, 16, 256,
        0L, 524288L, 524288L);
}